// Round 10
// baseline (948.568 us; speedup 1.0000x reference)
//
#include <hip/hip_runtime.h>
#include <hip/hip_bf16.h>
#include <math.h>

// EvolveGCN-H on MI355X. B=2, T=8, N=10000, F=128, E=320000, 2 layers.
// R10: prop2 — 2 timesteps per wave (16 edges x 4 subwords lanes, 4 gather
// streams in flight, staged split-merge epilogue), panels still 2.56MB/XCD;
// gemm A-staging reverted to row-major As[128][33] (kills 8-way write
// conflict of the transposed 132-stride layout).

#define BB 2
#define TT 8
#define FF 128
#define GG 384   // 3*FF
#define BINS 8192
#define CAP 512

typedef float v4f __attribute__((ext_vector_type(4)));

__device__ __forceinline__ float bf2f(unsigned short u) {
  return __uint_as_float((unsigned)u << 16);
}
__device__ __forceinline__ unsigned short f2bf(float f) {  // RNE
  unsigned x = __float_as_uint(f);
  unsigned r = ((x >> 16) & 1u) + 0x7fffu;
  return (unsigned short)((x + r) >> 16);
}

// ---------------- detect (int64 vs int32) + pnorm, one dispatch -------------
__global__ void prep_kernel(const int* __restrict__ ei32, int E, int* __restrict__ flag,
                            const float* __restrict__ p, float* __restrict__ pinv) {
  if (blockIdx.x == 0) {
    int step = E / 256;
    int e = threadIdx.x * step;
    if (ei32[2 * e + 1] != 0) *flag = 1;   // benign race, same value
  } else {
    int c = blockIdx.x - 1, tid = threadIdx.x;
    float s = 0.f;
    if (tid < 128) { float v = p[c * FF + tid]; s = v * v; }
    for (int o = 32; o; o >>= 1) s += __shfl_xor(s, o, 64);
    __shared__ float red[4];
    if ((tid & 63) == 0) red[tid >> 6] = s;
    __syncthreads();
    if (tid == 0) pinv[c] = 1.0f / sqrtf(red[0] + red[1] + red[2] + red[3]);
  }
}

__device__ __forceinline__ void edge_fetch(const void* ei, int is32, int E,
                                           int e, const float* ew,
                                           int& row, int& col, float& w) {
  if (e < E) {
    if (is32) {
      const int* p = (const int*)ei;
      row = p[e]; col = p[E + e];
    } else {
      const long long* p = (const long long*)ei;
      row = (int)p[e]; col = (int)p[(long long)E + e];
    }
    w = ew[e];
  } else {           // self loop
    row = col = e - E; w = 1.0f;
  }
}

__global__ void hist_kernel(const void* ei, const int* flag, int E, int N,
                            const float* __restrict__ ew,
                            float* __restrict__ deg, int* __restrict__ counts) {
  int e = blockIdx.x * 256 + threadIdx.x;
  if (e >= E + N) return;
  int row, col; float w;
  edge_fetch(ei, *flag, E, e, ew, row, col, w);
  atomicAdd(&deg[col], w);
  atomicAdd(&counts[col], 1);
}

// ---- offsets scan (shuffle-based, 1 barrier) + dinv, one dispatch ----------
__global__ __launch_bounds__(1024) void scan_kernel(
    const int* __restrict__ counts, const float* __restrict__ deg,
    int* __restrict__ offsets, float* __restrict__ dinv, int N, int EN) {
  __shared__ int wtot[16];
  int tid = threadIdx.x, lane = tid & 63, wid = tid >> 6;
  int base = tid * 10;
  int lc[10]; int s10 = 0;
#pragma unroll
  for (int q = 0; q < 10; ++q) {
    int idx = base + q;
    int cv = (idx < N) ? counts[idx] : 0;
    lc[q] = cv; s10 += cv;
    if (idx < N) {
      float d = deg[idx];
      dinv[idx] = (d > 0.f) ? 1.0f / sqrtf(d) : 0.f;
    }
  }
  int s = s10;
#pragma unroll
  for (int off = 1; off <= 32; off <<= 1) {
    int v = __shfl_up(s, off, 64);
    if (lane >= off) s += v;
  }
  if (lane == 63) wtot[wid] = s;
  __syncthreads();
  int pre = 0;
  for (int w2 = 0; w2 < wid; ++w2) pre += wtot[w2];
  int run = pre + s - s10;   // exclusive prefix
#pragma unroll
  for (int q = 0; q < 10; ++q) {
    int idx = base + q;
    if (idx < N) { offsets[idx] = run; run += lc[q]; }
  }
  if (tid == 0) offsets[N] = EN;
}

__global__ void scatter_kernel(const void* ei, const int* flag, int E, int N,
                               const float* __restrict__ ew,
                               const float* __restrict__ dinv,
                               const int* __restrict__ offs,
                               int* __restrict__ cursors,
                               int2* __restrict__ ep) {
  int e = blockIdx.x * 256 + threadIdx.x;
  if (e >= E + N) return;
  int row, col; float w;
  edge_fetch(ei, *flag, E, e, ew, row, col, w);
  int pos = atomicAdd(&cursors[col], 1);
  ep[offs[col] + pos] = make_int2(row, __float_as_int(dinv[row] * w * dinv[col]));
}

// ------- CSR prop for x (fp32, all 8 t): 2 timesteps per wave ----------------
// lid bits: tp = lid&3 (t-pair), fq0 = (lid>>2)&1, s = lid>>3;
// fqh = s/NG, vg = s%NG, fq = fqh*2+fq0 (8 x 16-feature passes).
// Panel (tp,fq) = 2t x 2b x N x 16 feats x 4B = 2.56MB -> one XCD's L2.
// 64 lanes = 16 edges (e=lane>>2) x 4 subwords (sub=lane&3, 16B each).
// 4 gather streams in flight per lane: (t0,b0) (t0,b1) (t1,b0) (t1,b1).
__global__ __launch_bounds__(256) void prop2_kernel(
    const float* __restrict__ x, size_t s_tstride, size_t s_bstride,
    float* __restrict__ dst, size_t d_tstride, size_t d_bstride,
    const int2* __restrict__ ep, const int* __restrict__ offs,
    const float* __restrict__ p, const float* __restrict__ pinv,
    unsigned long long* __restrict__ keys, int* __restrict__ hist,
    int N, int NG) {
  int lid = blockIdx.x;
  int tp = lid & 3;
  int fq0 = (lid >> 2) & 1;
  int s = lid >> 3;
  int fqh = s / NG, vg = s - fqh * NG;
  int fq = fqh * 2 + fq0;
  int lane = threadIdx.x & 63;
  int e = lane >> 2, sub = lane & 3;
  int v = vg * 4 + (threadIdx.x >> 6);
  if (v >= N) return;
  int e0 = offs[v], e1 = offs[v + 1];
  int t0 = tp * 2;
  const uint4* g00 = (const uint4*)(x + (size_t)t0 * s_tstride);
  const uint4* g01 = (const uint4*)(x + (size_t)t0 * s_tstride + s_bstride);
  const uint4* g10 = (const uint4*)(x + (size_t)(t0 + 1) * s_tstride);
  const uint4* g11 = (const uint4*)(x + (size_t)(t0 + 1) * s_tstride + s_bstride);
  int fo16 = fq * 4 + sub;    // uint4 index within the 32-uint4 row
  float a00[4] = {}, a01[4] = {}, a10[4] = {}, a11[4] = {};
  for (int base = e0; base < e1; base += 64) {
    int cnt = e1 - base; if (cnt > 64) cnt = 64;
    int2 m = make_int2(0, 0);
    if (lane < cnt) m = ep[base + lane];
    for (int i = 0; i < cnt; i += 16) {
      int srcl = i + e;
      int row = __shfl(m.x, srcl, 64);
      float wv = __int_as_float(__shfl(m.y, srcl, 64));
      if (srcl >= cnt) wv = 0.f;
      size_t r = (size_t)row * 32 + fo16;
      uint4 r00 = g00[r], r01 = g01[r], r10 = g10[r], r11 = g11[r];
      a00[0] += wv * __uint_as_float(r00.x);
      a00[1] += wv * __uint_as_float(r00.y);
      a00[2] += wv * __uint_as_float(r00.z);
      a00[3] += wv * __uint_as_float(r00.w);
      a01[0] += wv * __uint_as_float(r01.x);
      a01[1] += wv * __uint_as_float(r01.y);
      a01[2] += wv * __uint_as_float(r01.z);
      a01[3] += wv * __uint_as_float(r01.w);
      a10[0] += wv * __uint_as_float(r10.x);
      a10[1] += wv * __uint_as_float(r10.y);
      a10[2] += wv * __uint_as_float(r10.z);
      a10[3] += wv * __uint_as_float(r10.w);
      a11[0] += wv * __uint_as_float(r11.x);
      a11[1] += wv * __uint_as_float(r11.y);
      a11[2] += wv * __uint_as_float(r11.z);
      a11[3] += wv * __uint_as_float(r11.w);
    }
  }
  // staged split-merge: xor32 keeps t-half, xor16 keeps b-half, xor8/4 sum.
  bool hi5 = (lane & 32) != 0;
  float k0[4], k1[4];
#pragma unroll
  for (int q = 0; q < 4; ++q) {
    float s0 = hi5 ? a10[q] : a00[q];   // my kept b0 stream
    float s1 = hi5 ? a11[q] : a01[q];   // my kept b1 stream
    float o0 = hi5 ? a00[q] : a10[q];   // partner's kept b0 stream
    float o1 = hi5 ? a01[q] : a11[q];
    k0[q] = s0 + __shfl_xor(o0, 32, 64);
    k1[q] = s1 + __shfl_xor(o1, 32, 64);
  }
  bool hi4 = (lane & 16) != 0;
  float kk[4];
#pragma unroll
  for (int q = 0; q < 4; ++q) {
    float sK = hi4 ? k1[q] : k0[q];
    float oK = hi4 ? k0[q] : k1[q];
    kk[q] = sK + __shfl_xor(oK, 16, 64);
  }
#pragma unroll
  for (int q = 0; q < 4; ++q) {
    kk[q] += __shfl_xor(kk[q], 8, 64);
    kk[q] += __shfl_xor(kk[q], 4, 64);
  }
  if ((e & 3) == 0) {                 // e in {0,4,8,12} -> (t,b) streams
    int tt = e >> 3, b = (e >> 2) & 1;
    float* ob = dst + (size_t)(t0 + tt) * d_tstride + (b ? d_bstride : 0);
    size_t fo = (size_t)v * FF + fq * 16 + sub * 4;
    v4f st = {kk[0], kk[1], kk[2], kk[3]};
    __builtin_nontemporal_store(st, (v4f*)(ob + fo));
  }
  if (p && fq == 0) {  // fused layer-0 scores for both t of the pair, both b
    int half = lane >> 5, i32 = lane & 31;
    float4 pp = ((const float4*)p)[i32];
#pragma unroll
    for (int tt = 0; tt < 2; ++tt) {
      const v4f* xr = (const v4f*)(half ? (tt ? g11 : g01) : (tt ? g10 : g00));
      v4f xv = __builtin_nontemporal_load(xr + (size_t)v * 32 + i32);
      float sc = xv.x * pp.x + xv.y * pp.y + xv.z * pp.z + xv.w * pp.w;
#pragma unroll
      for (int o = 1; o <= 16; o <<= 1) sc += __shfl_xor(sc, o, 64);
      if (i32 == 0) {
        float ss = sc * (*pinv);
        unsigned u = __float_as_uint(ss);
        u = (u & 0x80000000u) ? ~u : (u | 0x80000000u);
        int tb = (t0 + tt) * 2 + half;
        keys[(size_t)tb * N + v] = ((unsigned long long)u << 32) | (unsigned)(~v);
        atomicAdd(&hist[tb * BINS + (u >> 19)], 1);
      }
    }
  }
}

// ------- CSR prop, bf16 source, single t (final-layer gather) ---------------
// Wave = 1 vertex; 64 lanes = 8 edges x 8 subwords; 2 fq passes of 64 feats.
__global__ __launch_bounds__(256) void propb_kernel(
    const unsigned short* __restrict__ srcv, size_t s_bstride,
    float* __restrict__ dst, size_t d_bstride,
    const int2* __restrict__ ep, const int* __restrict__ offs,
    int N, int NG) {
  int lid = blockIdx.x;
  int fq = lid / NG, vg = lid - fq * NG;
  int lane = threadIdx.x & 63;
  int e = lane >> 3, sub = lane & 7;
  int v = vg * 4 + (threadIdx.x >> 6);
  if (v >= N) return;
  int e0 = offs[v], e1 = offs[v + 1];
  const uint4* g0 = (const uint4*)srcv;
  const uint4* g1 = (const uint4*)(srcv + s_bstride);
  int fqs = fq * 8;
  float acc0[8] = {}, acc1[8] = {};
  for (int base = e0; base < e1; base += 64) {
    int cnt = e1 - base; if (cnt > 64) cnt = 64;
    int2 m = make_int2(0, 0);
    if (lane < cnt) m = ep[base + lane];
    for (int i = 0; i < cnt; i += 8) {
      int srcl = i + e;
      int row = __shfl(m.x, srcl, 64);
      float wv = __int_as_float(__shfl(m.y, srcl, 64));
      if (srcl >= cnt) wv = 0.f;
      size_t r = (size_t)row * 16 + fqs + sub;
      uint4 ra = g0[r], rb = g1[r];
      acc0[0] += wv * bf2f(ra.x & 0xffff); acc0[1] += wv * bf2f(ra.x >> 16);
      acc0[2] += wv * bf2f(ra.y & 0xffff); acc0[3] += wv * bf2f(ra.y >> 16);
      acc0[4] += wv * bf2f(ra.z & 0xffff); acc0[5] += wv * bf2f(ra.z >> 16);
      acc0[6] += wv * bf2f(ra.w & 0xffff); acc0[7] += wv * bf2f(ra.w >> 16);
      acc1[0] += wv * bf2f(rb.x & 0xffff); acc1[1] += wv * bf2f(rb.x >> 16);
      acc1[2] += wv * bf2f(rb.y & 0xffff); acc1[3] += wv * bf2f(rb.y >> 16);
      acc1[4] += wv * bf2f(rb.z & 0xffff); acc1[5] += wv * bf2f(rb.z >> 16);
      acc1[6] += wv * bf2f(rb.w & 0xffff); acc1[7] += wv * bf2f(rb.w >> 16);
    }
  }
#pragma unroll
  for (int mk = 8; mk <= 32; mk <<= 1) {
#pragma unroll
    for (int q = 0; q < 8; ++q) {
      acc0[q] += __shfl_xor(acc0[q], mk, 64);
      acc1[q] += __shfl_xor(acc1[q], mk, 64);
    }
  }
  if (e < 2) {
    float* ob = dst + (e ? d_bstride : 0);
    float* av = e ? acc1 : acc0;
    size_t fo = (size_t)v * FF + fq * 64 + sub * 8;
    v4f st0 = {av[0], av[1], av[2], av[3]};
    v4f st1 = {av[4], av[5], av[6], av[7]};
    __builtin_nontemporal_store(st0, (v4f*)(ob + fo));
    __builtin_nontemporal_store(st1, (v4f*)(ob + fo + 4));
  }
}

// ------- select threshold + filter + wave-register sort; grid (2b, 8t) -----
__device__ __forceinline__ unsigned long long shfl_xor_u64(unsigned long long x,
                                                           int m) {
  unsigned lo = (unsigned)x, hi = (unsigned)(x >> 32);
  lo = __shfl_xor(lo, m, 64);
  hi = __shfl_xor(hi, m, 64);
  return ((unsigned long long)hi << 32) | lo;
}

__global__ __launch_bounds__(1024) void selectsort_kernel(
    const unsigned long long* __restrict__ keys, const int* __restrict__ hist,
    int N, int* __restrict__ idx_sel, float* __restrict__ gate_sel) {
  int tb = blockIdx.y * 2 + blockIdx.x, tid = threadIdx.x;
  int lane = tid & 63, wid = tid >> 6;   // 16 waves
  const int* h = hist + tb * BINS;
  __shared__ int wtot[16];
  __shared__ unsigned long long cand[CAP];
  __shared__ int sT, ncnt;
  int base = tid * 8;
  int lc[8]; int local = 0;
#pragma unroll
  for (int q = 0; q < 8; ++q) { lc[q] = h[base + q]; local += lc[q]; }
  if (tid == 0) ncnt = 0;
  int s = local;
#pragma unroll
  for (int off = 1; off <= 32; off <<= 1) {
    int v = __shfl_down(s, off, 64);
    if (lane + off < 64) s += v;
  }
  if (lane == 0) wtot[wid] = s;
  __syncthreads();
  int above_w = 0;
  for (int w2 = wid + 1; w2 < 16; ++w2) above_w += wtot[w2];
  int incl = above_w + s;
  int above = incl - local;
  if (above < 128 && incl >= 128) {
    int cnt = above;
#pragma unroll
    for (int q = 7; q >= 0; --q) {
      int c = lc[q];
      if (cnt + c >= 128) { sT = base + q; break; }
      cnt += c;
    }
  }
  __syncthreads();
  int T = sT;
  for (int i = tid; i < N; i += 1024) {
    unsigned long long kk = keys[(size_t)tb * N + i];
    if ((int)(kk >> 51) >= T) {
      int pos = atomicAdd(&ncnt, 1);
      if (pos < CAP) cand[pos] = kk;
    }
  }
  __syncthreads();
  if (tid < 64) {
    int nc = ncnt < CAP ? ncnt : CAP;
    unsigned long long v[8];
#pragma unroll
    for (int r = 0; r < 8; ++r) {
      int e = r * 64 + lane;
      v[r] = (e < nc) ? cand[e] : 0ULL;
    }
    for (int k = 2; k <= 512; k <<= 1)
      for (int j = k >> 1; j > 0; j >>= 1) {
        if (j >= 64) {
          int rj = j >> 6;
#pragma unroll
          for (int r = 0; r < 8; ++r)
            if (!(r & rj)) {
              int r2 = r | rj;
              bool up = (((r * 64) & k) != 0);
              unsigned long long a = v[r], c = v[r2];
              bool sw = up ? (a > c) : (a < c);
              if (sw) { v[r] = c; v[r2] = a; }
            }
        } else {
#pragma unroll
          for (int r = 0; r < 8; ++r) {
            unsigned long long o = shfl_xor_u64(v[r], j);
            int e = r * 64 + lane;
            bool up = (e & k) != 0;
            bool lower = (lane & j) == 0;
            unsigned long long mn = v[r] < o ? v[r] : o;
            unsigned long long mx = v[r] < o ? o : v[r];
            v[r] = (lower == up) ? mn : mx;
          }
        }
      }
#pragma unroll
    for (int r = 0; r < 2; ++r) {
      int e = r * 64 + lane;
      unsigned long long kk = v[r];
      unsigned n = ~((unsigned)kk);
      unsigned u = (unsigned)(kk >> 32);
      float sc = (u & 0x80000000u) ? __uint_as_float(u & 0x7FFFFFFFu)
                                   : __uint_as_float(~u);
      idx_sel[tb * 128 + e] = (int)n;
      gate_sel[tb * 128 + e] = tanhf(sc);
    }
  }
}

// ------- whole W GRU chain (8 steps) in one kernel; grid (2b, 32 jtiles) ----
template <int SRC_BF16>
__global__ __launch_bounds__(256) void wchain_kernel(
    const void* __restrict__ srcv, size_t src_tstride, size_t src_bstride,
    const int* __restrict__ idx_sel, const float* __restrict__ gate_sel,
    const float* __restrict__ Winit,   // [FF m][FF j]; h[j][m] = Winit[m][j]
    const float* __restrict__ wih, const float* __restrict__ whh,
    const float* __restrict__ bih, const float* __restrict__ bhh,
    float* __restrict__ snap) {        // [t*2+b][k][j]
  int b = blockIdx.x, j0 = blockIdx.y * 4;
  int tid = threadIdx.x, side = tid >> 7, kl = tid & 127;
  __shared__ float pooled[4][FF];
  __shared__ float hbuf[4][FF];
  __shared__ float ghbuf[3][4][FF];
  for (int e = tid; e < 4 * FF; e += 256) {
    int j = e >> 7, m = e & 127;
    hbuf[j][m] = Winit[m * FF + j0 + j];
  }
  float b0 = side ? bhh[kl] : bih[kl];
  float b1 = side ? bhh[FF + kl] : bih[FF + kl];
  float b2 = side ? bhh[2 * FF + kl] : bih[2 * FF + kl];
  const float* wmat = side ? whh : wih;
  const float4* w0p = (const float4*)(wmat + (size_t)(0 * FF + kl) * FF);
  const float4* w1p = (const float4*)(wmat + (size_t)(1 * FF + kl) * FF);
  const float4* w2p = (const float4*)(wmat + (size_t)(2 * FF + kl) * FF);
  for (int t = 0; t < TT; ++t) {
    int tb = t * 2 + b;
    __syncthreads();   // protects pooled overwrite + hbuf update visibility
    for (int e = tid; e < 4 * FF; e += 256) {
      int j = e >> 7, m = e & 127;
      int n = idx_sel[tb * 128 + j0 + j];
      float g = gate_sel[tb * 128 + j0 + j];
      size_t off = (size_t)t * src_tstride + (size_t)b * src_bstride +
                   (size_t)n * FF + m;
      float xv;
      if constexpr (SRC_BF16) xv = bf2f(((const unsigned short*)srcv)[off]);
      else                    xv = ((const float*)srcv)[off];
      pooled[j][m] = xv * g;
    }
    __syncthreads();
    const float4* vsrc = (const float4*)(side ? &hbuf[0][0] : &pooled[0][0]);
    float acc0[4] = {}, acc1[4] = {}, acc2[4] = {};
    for (int mq = 0; mq < 32; ++mq) {
      float4 w0 = w0p[mq], w1 = w1p[mq], w2 = w2p[mq];
#pragma unroll
      for (int j = 0; j < 4; ++j) {
        float4 v = vsrc[j * 32 + mq];
        acc0[j] += v.x * w0.x + v.y * w0.y + v.z * w0.z + v.w * w0.w;
        acc1[j] += v.x * w1.x + v.y * w1.y + v.z * w1.z + v.w * w1.w;
        acc2[j] += v.x * w2.x + v.y * w2.y + v.z * w2.z + v.w * w2.w;
      }
    }
    if (side) {
#pragma unroll
      for (int j = 0; j < 4; ++j) {
        ghbuf[0][j][kl] = acc0[j] + b0;
        ghbuf[1][j][kl] = acc1[j] + b1;
        ghbuf[2][j][kl] = acc2[j] + b2;
      }
    }
    __syncthreads();
    if (!side) {
#pragma unroll
      for (int j = 0; j < 4; ++j) {
        float rr = 1.0f / (1.0f + expf(-(acc0[j] + b0 + ghbuf[0][j][kl])));
        float zz = 1.0f / (1.0f + expf(-(acc1[j] + b1 + ghbuf[1][j][kl])));
        float nn = tanhf(acc2[j] + b2 + rr * ghbuf[2][j][kl]);
        float h = hbuf[j][kl];
        float hn = (1.0f - zz) * nn + zz * h;
        hbuf[j][kl] = hn;
        snap[((size_t)tb * FF + kl) * FF + j0 + j] = hn;
      }
    }
  }
}

// ------- batched GEMM + bias + relu (+ optional fused next-layer scores) ----
// out[tb][n][:] = relu(A[tb][n][:] @ Wsnap[tb] + bias); grid (ceil(N/128), 2b, Tz)
// Output: fp32 (outf) or bf16 (outb) — exactly one non-null.
__global__ __launch_bounds__(256) void gemm_kernel(
    const float* __restrict__ A, size_t a_tstride, size_t a_bstride,
    const float* __restrict__ Wsnap, const float* __restrict__ bias,
    float* __restrict__ outf, unsigned short* __restrict__ outb,
    size_t o_tstride, size_t o_bstride,
    const float* __restrict__ p1, const float* __restrict__ pinv1,
    unsigned long long* __restrict__ keys, int* __restrict__ hist, int N) {
  int nb = blockIdx.x, b = blockIdx.y, t = blockIdx.z;
  int tb = t * 2 + b;
  __shared__ float As[128][33];    // row-major, +1 pad: conflict-free staging
  __shared__ float Bs[32][128];
  __shared__ float spart[128][17];
  __shared__ float p1s[128];
  int tid = threadIdx.x;
  int tc = tid & 15, tr = tid >> 4;
  if (p1 && tid < 128) p1s[tid] = p1[tid];
  float acc[8][8] = {};
  const float* Ab = A + (size_t)t * a_tstride + (size_t)b * a_bstride;
  const float* Wb = Wsnap + (size_t)tb * FF * FF;
  for (int kc = 0; kc < 4; ++kc) {
    int k0 = kc * 32;
    __syncthreads();
    for (int e = tid; e < 128 * 32; e += 256) {
      int r = e >> 5, kk = e & 31;
      int n = nb * 128 + r;
      As[r][kk] = (n < N) ? Ab[(size_t)n * FF + k0 + kk] : 0.f;
    }
    for (int e = tid; e < 32 * 128; e += 256) {
      int r = e >> 7, dd = e & 127;
      Bs[r][dd] = Wb[(k0 + r) * FF + dd];
    }
    __syncthreads();
#pragma unroll 4
    for (int kk = 0; kk < 32; ++kk) {
      float av[8];
#pragma unroll
      for (int i = 0; i < 8; ++i) av[i] = As[tr * 8 + i][kk];
      const float4* brow = (const float4*)Bs[kk];
      float4 b0 = brow[tc * 2], b1 = brow[tc * 2 + 1];
      float bv[8] = {b0.x, b0.y, b0.z, b0.w, b1.x, b1.y, b1.z, b1.w};
#pragma unroll
      for (int i = 0; i < 8; ++i)
#pragma unroll
        for (int j = 0; j < 8; ++j) acc[i][j] += av[i] * bv[j];
    }
  }
  float bb[8];
#pragma unroll
  for (int j = 0; j < 8; ++j) bb[j] = bias[tc * 8 + j];
  size_t obase = (size_t)t * o_tstride + (size_t)b * o_bstride;
#pragma unroll
  for (int i = 0; i < 8; ++i) {
    int n = nb * 128 + tr * 8 + i;
    float v[8]; float part = 0.f;
#pragma unroll
    for (int j = 0; j < 8; ++j) {
      v[j] = fmaxf(acc[i][j] + bb[j], 0.f);
      if (p1) part += v[j] * p1s[tc * 8 + j];
    }
    if (n < N) {
      if (outb) {
        unsigned short* dst = outb + obase + (size_t)n * FF + tc * 8;
        uint4 pk;
        pk.x = (unsigned)f2bf(v[0]) | ((unsigned)f2bf(v[1]) << 16);
        pk.y = (unsigned)f2bf(v[2]) | ((unsigned)f2bf(v[3]) << 16);
        pk.z = (unsigned)f2bf(v[4]) | ((unsigned)f2bf(v[5]) << 16);
        pk.w = (unsigned)f2bf(v[6]) | ((unsigned)f2bf(v[7]) << 16);
        *(uint4*)dst = pk;
      } else {
        float4* dst = (float4*)(outf + obase + (size_t)n * FF + tc * 8);
        dst[0] = make_float4(v[0], v[1], v[2], v[3]);
        dst[1] = make_float4(v[4], v[5], v[6], v[7]);
      }
    }
    if (p1) spart[tr * 8 + i][tc] = part;
  }
  if (p1) {
    __syncthreads();
    if (tid < 128) {
      int n = nb * 128 + tid;
      if (n < N) {
        float s = 0.f;
#pragma unroll
        for (int q = 0; q < 16; ++q) s += spart[tid][q];
        s *= *pinv1;
        unsigned u = __float_as_uint(s);
        u = (u & 0x80000000u) ? ~u : (u | 0x80000000u);
        keys[(size_t)tb * N + n] = ((unsigned long long)u << 32) | (unsigned)(~n);
        atomicAdd(&hist[tb * BINS + (u >> 19)], 1);
      }
    }
  }
}

// ---------------- host ----------------
extern "C" void kernel_launch(void* const* d_in, const int* in_sizes, int n_in,
                              void* d_out, int out_size, void* d_ws, size_t ws_size,
                              hipStream_t stream) {
  const float* x   = (const float*)d_in[0];
  const void*  ei  = d_in[1];
  const float* ew  = (const float*)d_in[2];
  const float* W0  = (const float*)d_in[3];
  const float* p   = (const float*)d_in[4];
  const float* wih = (const float*)d_in[5];
  const float* whh = (const float*)d_in[6];
  const float* bih = (const float*)d_in[7];
  const float* bhh = (const float*)d_in[8];
  const float* bias= (const float*)d_in[9];

  const int E  = in_sizes[2];
  const int N  = in_sizes[0] / (BB * TT * FF);
  const int EN = E + N;
  const size_t NF = (size_t)N * FF;
  const int NG = (N + 3) / 4;

  char* w = (char*)d_ws;
  auto alloc = [&](size_t bytes) -> char* {
    char* r = w; w += (bytes + 255) & ~(size_t)255; return r;
  };
  // ---- zero region (single memset) ----
  char* zbeg = w;
  float* deg      = (float*)alloc((size_t)N * 4);
  int*   counts   = (int*)  alloc((size_t)N * 4);
  int*   cursors  = (int*)  alloc((size_t)N * 4);
  int*   flag     = (int*)  alloc(4);
  int*   hist     = (int*)  alloc((size_t)2 * TT * BB * BINS * 4);
  char* zend = w;
  // ---- rest ----
  int*   offsets  = (int*)  alloc((size_t)(N + 1) * 4);
  float* dinv     = (float*)alloc((size_t)N * 4);
  float* pinv     = (float*)alloc(2 * 4);
  int2*  ep       = (int2*) alloc((size_t)EN * 8);
  unsigned long long* keys0 = (unsigned long long*)alloc((size_t)TT * BB * N * 8);
  unsigned long long* keys1 = (unsigned long long*)alloc((size_t)TT * BB * N * 8);
  int*   idx0     = (int*)  alloc((size_t)TT * BB * 128 * 4);
  float* gate0    = (float*)alloc((size_t)TT * BB * 128 * 4);
  int*   idx1     = (int*)  alloc((size_t)TT * BB * 128 * 4);
  float* gate1    = (float*)alloc((size_t)TT * BB * 128 * 4);
  float* W0snap   = (float*)alloc((size_t)TT * BB * FF * FF * 4);
  float* W1snap   = (float*)alloc((size_t)TT * BB * FF * FF * 4);
  float* xp       = (float*)alloc((size_t)TT * BB * NF * 4);  // A·x[t], fp32
  unsigned short* act0 = (unsigned short*)alloc((size_t)TT * BB * NF * 2); // bf16
  float* xq       = (float*)alloc((size_t)BB * NF * 4);       // A·act0[7], fp32
  int* hist0 = hist;
  int* hist1 = hist + (size_t)TT * BB * BINS;

  hipMemsetAsync(zbeg, 0, (size_t)(zend - zbeg), stream);

  // graph preprocessing (CSR by destination + symmetric norm)
  prep_kernel<<<3, 256, 0, stream>>>((const int*)ei, E, flag, p, pinv);
  hist_kernel<<<(EN + 255) / 256, 256, 0, stream>>>(ei, flag, E, N, ew, deg, counts);
  scan_kernel<<<1, 1024, 0, stream>>>(counts, deg, offsets, dinv, N, EN);
  scatter_kernel<<<(EN + 255) / 256, 256, 0, stream>>>(ei, flag, E, N, ew, dinv,
                                                       offsets, cursors, ep);

  // xp[t][b] = A · x[b][t]: 8x16-feat passes, 2 t per wave, panels XCD-pinned
  prop2_kernel<<<NG * 32, 256, 0, stream>>>(
      x, NF, (size_t)TT * NF, xp, (size_t)BB * NF, NF,
      ep, offsets, p, pinv, keys0, hist0, N, NG);

  selectsort_kernel<<<dim3(BB, TT), 1024, 0, stream>>>(
      keys0, hist0, N, idx0, gate0);

  // whole layer-0 W chain (8 GRU steps)
  wchain_kernel<0><<<dim3(BB, 32), 256, 0, stream>>>(
      x, NF, (size_t)TT * NF, idx0, gate0, W0,
      wih, whh, bih, bhh, W0snap);

  // act0[t][b] = relu(xp @ W0_t + bias0) -> bf16, fused layer-1 scores (fp32)
  gemm_kernel<<<dim3((N + 127) / 128, BB, TT), 256, 0, stream>>>(
      xp, (size_t)BB * NF, NF, W0snap, bias,
      nullptr, act0, (size_t)BB * NF, NF,
      p + FF, pinv + 1, keys1, hist1, N);

  selectsort_kernel<<<dim3(BB, TT), 1024, 0, stream>>>(
      keys1, hist1, N, idx1, gate1);

  // layer-1 W chain (bf16 pooled gathers)
  wchain_kernel<1><<<dim3(BB, 32), 256, 0, stream>>>(
      act0, (size_t)BB * NF, NF, idx1, gate1, W0 + FF * FF,
      wih + (size_t)GG * FF, whh + (size_t)GG * FF,
      bih + GG, bhh + GG, W1snap);

  // xq[b] = A · act0[7][b]  (bf16 gather, fp32 accumulate; 2 fq passes)
  propb_kernel<<<NG * 2, 256, 0, stream>>>(
      act0 + (size_t)(TT - 1) * BB * NF, NF, xq, NF,
      ep, offsets, N, NG);

  // d_out = relu(xq @ W1_7 + bias1), fp32
  gemm_kernel<<<dim3((N + 127) / 128, BB, 1), 256, 0, stream>>>(
      xq, 0, NF, W1snap + (size_t)(TT - 1) * BB * FF * FF, bias + FF,
      (float*)d_out, nullptr, 0, NF,
      nullptr, nullptr, nullptr, nullptr, N);
}

// Round 11
// 823.314 us; speedup vs baseline: 1.1521x; 1.1521x over previous
//
#include <hip/hip_runtime.h>
#include <hip/hip_bf16.h>
#include <math.h>

// EvolveGCN-H on MI355X. B=2, T=8, N=10000, F=128, E=320000, 2 layers.
// R11: revert prop to R9 structure (128B-contiguous per-edge slices; R10's
// 64B slices caused 6x line-granularity over-fetch, 199->306us). Keep R10
// row-major conflict-free gemm staging. wchain j-tile 4->2 (2x blocks).

#define BB 2
#define TT 8
#define FF 128
#define GG 384   // 3*FF
#define BINS 8192
#define CAP 512

typedef float v4f __attribute__((ext_vector_type(4)));

__device__ __forceinline__ float bf2f(unsigned short u) {
  return __uint_as_float((unsigned)u << 16);
}
__device__ __forceinline__ unsigned short f2bf(float f) {  // RNE
  unsigned x = __float_as_uint(f);
  unsigned r = ((x >> 16) & 1u) + 0x7fffu;
  return (unsigned short)((x + r) >> 16);
}

// ---------------- detect (int64 vs int32) + pnorm, one dispatch -------------
__global__ void prep_kernel(const int* __restrict__ ei32, int E, int* __restrict__ flag,
                            const float* __restrict__ p, float* __restrict__ pinv) {
  if (blockIdx.x == 0) {
    int step = E / 256;
    int e = threadIdx.x * step;
    if (ei32[2 * e + 1] != 0) *flag = 1;   // benign race, same value
  } else {
    int c = blockIdx.x - 1, tid = threadIdx.x;
    float s = 0.f;
    if (tid < 128) { float v = p[c * FF + tid]; s = v * v; }
    for (int o = 32; o; o >>= 1) s += __shfl_xor(s, o, 64);
    __shared__ float red[4];
    if ((tid & 63) == 0) red[tid >> 6] = s;
    __syncthreads();
    if (tid == 0) pinv[c] = 1.0f / sqrtf(red[0] + red[1] + red[2] + red[3]);
  }
}

__device__ __forceinline__ void edge_fetch(const void* ei, int is32, int E,
                                           int e, const float* ew,
                                           int& row, int& col, float& w) {
  if (e < E) {
    if (is32) {
      const int* p = (const int*)ei;
      row = p[e]; col = p[E + e];
    } else {
      const long long* p = (const long long*)ei;
      row = (int)p[e]; col = (int)p[(long long)E + e];
    }
    w = ew[e];
  } else {           // self loop
    row = col = e - E; w = 1.0f;
  }
}

__global__ void hist_kernel(const void* ei, const int* flag, int E, int N,
                            const float* __restrict__ ew,
                            float* __restrict__ deg, int* __restrict__ counts) {
  int e = blockIdx.x * 256 + threadIdx.x;
  if (e >= E + N) return;
  int row, col; float w;
  edge_fetch(ei, *flag, E, e, ew, row, col, w);
  atomicAdd(&deg[col], w);
  atomicAdd(&counts[col], 1);
}

// ---- offsets scan (shuffle-based, 1 barrier) + dinv, one dispatch ----------
__global__ __launch_bounds__(1024) void scan_kernel(
    const int* __restrict__ counts, const float* __restrict__ deg,
    int* __restrict__ offsets, float* __restrict__ dinv, int N, int EN) {
  __shared__ int wtot[16];
  int tid = threadIdx.x, lane = tid & 63, wid = tid >> 6;
  int base = tid * 10;
  int lc[10]; int s10 = 0;
#pragma unroll
  for (int q = 0; q < 10; ++q) {
    int idx = base + q;
    int cv = (idx < N) ? counts[idx] : 0;
    lc[q] = cv; s10 += cv;
    if (idx < N) {
      float d = deg[idx];
      dinv[idx] = (d > 0.f) ? 1.0f / sqrtf(d) : 0.f;
    }
  }
  int s = s10;
#pragma unroll
  for (int off = 1; off <= 32; off <<= 1) {
    int v = __shfl_up(s, off, 64);
    if (lane >= off) s += v;
  }
  if (lane == 63) wtot[wid] = s;
  __syncthreads();
  int pre = 0;
  for (int w2 = 0; w2 < wid; ++w2) pre += wtot[w2];
  int run = pre + s - s10;   // exclusive prefix
#pragma unroll
  for (int q = 0; q < 10; ++q) {
    int idx = base + q;
    if (idx < N) { offsets[idx] = run; run += lc[q]; }
  }
  if (tid == 0) offsets[N] = EN;
}

__global__ void scatter_kernel(const void* ei, const int* flag, int E, int N,
                               const float* __restrict__ ew,
                               const float* __restrict__ dinv,
                               const int* __restrict__ offs,
                               int* __restrict__ cursors,
                               int2* __restrict__ ep) {
  int e = blockIdx.x * 256 + threadIdx.x;
  if (e >= E + N) return;
  int row, col; float w;
  edge_fetch(ei, *flag, E, e, ew, row, col, w);
  int pos = atomicAdd(&cursors[col], 1);
  ep[offs[col] + pos] = make_int2(row, __float_as_int(dinv[row] * w * dinv[col]));
}

// ------- CSR prop, locality-engineered (R9 structure) -----------------------
// 1D grid = NG * NFQ * nT. If T8: t = lid&7 (XCD pin), s = lid>>3;
// else t = 0, s = lid. fq = s/NG (slow), vg = s%NG. Wave = 1 vertex.
// 64 lanes = 8 edges (e=lane>>3) x 8 subwords (sub=lane&7, 16B each) —
// 128B contiguous per edge slice (full cache lines; do NOT shrink).
// Edge meta: one cached lane-parallel int2 load per 64-edge chunk + shfl.
template <int SRC_BF16>
__global__ __launch_bounds__(256) void prop_kernel(
    const void* __restrict__ srcv, size_t s_tstride, size_t s_bstride,
    float* __restrict__ dst, size_t d_tstride, size_t d_bstride,
    const int2* __restrict__ ep, const int* __restrict__ offs,
    const float* __restrict__ p, const float* __restrict__ pinv,
    unsigned long long* __restrict__ keys, int* __restrict__ hist,
    int N, int NG, int t8) {
  constexpr int PER = SRC_BF16 ? 8 : 4;      // feats per lane per pass
  constexpr int RSU = SRC_BF16 ? 16 : 32;    // row stride in 16B units
  int lid = blockIdx.x;
  int t, s;
  if (t8) { t = lid & 7; s = lid >> 3; } else { t = 0; s = lid; }
  int fq = s / NG, vg = s - fq * NG;
  int lane = threadIdx.x & 63;
  int e = lane >> 3, sub = lane & 7;
  int v = vg * 4 + (threadIdx.x >> 6);
  if (v >= N) return;
  int e0 = offs[v], e1 = offs[v + 1];
  size_t o0 = (size_t)t * s_tstride, o1 = o0 + s_bstride;
  const uint4* g0;
  const uint4* g1;
  if constexpr (SRC_BF16) {
    g0 = (const uint4*)((const unsigned short*)srcv + o0);
    g1 = (const uint4*)((const unsigned short*)srcv + o1);
  } else {
    g0 = (const uint4*)((const float*)srcv + o0);
    g1 = (const uint4*)((const float*)srcv + o1);
  }
  int fqs = fq * 8;   // subword offset of this pass
  float acc0[PER], acc1[PER];
#pragma unroll
  for (int q = 0; q < PER; ++q) { acc0[q] = 0.f; acc1[q] = 0.f; }
  for (int base = e0; base < e1; base += 64) {
    int cnt = e1 - base; if (cnt > 64) cnt = 64;
    // one cached wave-wide meta load for up to 64 edges
    int2 m = make_int2(0, 0);
    if (lane < cnt) m = ep[base + lane];
    for (int i = 0; i < cnt; i += 8) {
      int srcl = i + e;                       // lane holding this edge's meta
      int row = __shfl(m.x, srcl, 64);
      float wv = __int_as_float(__shfl(m.y, srcl, 64));
      if (srcl >= cnt) wv = 0.f;              // tail: row 0 (safe), weight 0
      size_t r = (size_t)row * RSU + fqs + sub;
      uint4 ra = g0[r], rb = g1[r];
      if constexpr (SRC_BF16) {
        acc0[0] += wv * bf2f(ra.x & 0xffff); acc0[1] += wv * bf2f(ra.x >> 16);
        acc0[2] += wv * bf2f(ra.y & 0xffff); acc0[3] += wv * bf2f(ra.y >> 16);
        acc0[4] += wv * bf2f(ra.z & 0xffff); acc0[5] += wv * bf2f(ra.z >> 16);
        acc0[6] += wv * bf2f(ra.w & 0xffff); acc0[7] += wv * bf2f(ra.w >> 16);
        acc1[0] += wv * bf2f(rb.x & 0xffff); acc1[1] += wv * bf2f(rb.x >> 16);
        acc1[2] += wv * bf2f(rb.y & 0xffff); acc1[3] += wv * bf2f(rb.y >> 16);
        acc1[4] += wv * bf2f(rb.z & 0xffff); acc1[5] += wv * bf2f(rb.z >> 16);
        acc1[6] += wv * bf2f(rb.w & 0xffff); acc1[7] += wv * bf2f(rb.w >> 16);
      } else {
        acc0[0] += wv * __uint_as_float(ra.x);
        acc0[1] += wv * __uint_as_float(ra.y);
        acc0[2] += wv * __uint_as_float(ra.z);
        acc0[3] += wv * __uint_as_float(ra.w);
        acc1[0] += wv * __uint_as_float(rb.x);
        acc1[1] += wv * __uint_as_float(rb.y);
        acc1[2] += wv * __uint_as_float(rb.z);
        acc1[3] += wv * __uint_as_float(rb.w);
      }
    }
  }
  // tree-merge the 8 edge groups (bits 3,4,5 of lane)
#pragma unroll
  for (int mk = 8; mk <= 32; mk <<= 1) {
#pragma unroll
    for (int q = 0; q < PER; ++q) {
      acc0[q] += __shfl_xor(acc0[q], mk, 64);
      acc1[q] += __shfl_xor(acc1[q], mk, 64);
    }
  }
  // e==0 lanes store batch0, e==1 lanes store batch1 (same reduced values)
  if (e < 2) {
    float* ob = dst + (size_t)t * d_tstride + (e ? d_bstride : 0);
    float* av = e ? acc1 : acc0;
    size_t fo = (size_t)v * FF + fq * (PER * 8) + sub * PER;
    v4f st0 = {av[0], av[1], av[2], av[3]};
    __builtin_nontemporal_store(st0, (v4f*)(ob + fo));
    if constexpr (SRC_BF16) {
      v4f st1 = {av[4], av[5], av[6], av[7]};
      __builtin_nontemporal_store(st1, (v4f*)(ob + fo + 4));
    }
  }
  if constexpr (!SRC_BF16) {
    if (p && fq == 0) {  // fused layer-0 scores; nontemporal full-row reads
      int half = lane >> 5, i32 = lane & 31;
      const v4f* xrow = (const v4f*)(half ? g1 : g0);
      v4f xv = __builtin_nontemporal_load(xrow + (size_t)v * 32 + i32);
      float4 pp = ((const float4*)p)[i32];
      float sc = xv.x * pp.x + xv.y * pp.y + xv.z * pp.z + xv.w * pp.w;
#pragma unroll
      for (int o = 1; o <= 16; o <<= 1) sc += __shfl_xor(sc, o, 64);
      if (i32 == 0) {
        float ss = sc * (*pinv);
        unsigned u = __float_as_uint(ss);
        u = (u & 0x80000000u) ? ~u : (u | 0x80000000u);
        int tb = t * 2 + half;
        keys[(size_t)tb * N + v] = ((unsigned long long)u << 32) | (unsigned)(~v);
        atomicAdd(&hist[tb * BINS + (u >> 19)], 1);
      }
    }
  }
}

// ------- select threshold + filter + wave-register sort; grid (2b, 8t) -----
__device__ __forceinline__ unsigned long long shfl_xor_u64(unsigned long long x,
                                                           int m) {
  unsigned lo = (unsigned)x, hi = (unsigned)(x >> 32);
  lo = __shfl_xor(lo, m, 64);
  hi = __shfl_xor(hi, m, 64);
  return ((unsigned long long)hi << 32) | lo;
}

__global__ __launch_bounds__(1024) void selectsort_kernel(
    const unsigned long long* __restrict__ keys, const int* __restrict__ hist,
    int N, int* __restrict__ idx_sel, float* __restrict__ gate_sel) {
  int tb = blockIdx.y * 2 + blockIdx.x, tid = threadIdx.x;
  int lane = tid & 63, wid = tid >> 6;   // 16 waves
  const int* h = hist + tb * BINS;
  __shared__ int wtot[16];
  __shared__ unsigned long long cand[CAP];
  __shared__ int sT, ncnt;
  int base = tid * 8;
  int lc[8]; int local = 0;
#pragma unroll
  for (int q = 0; q < 8; ++q) { lc[q] = h[base + q]; local += lc[q]; }
  if (tid == 0) ncnt = 0;
  int s = local;
#pragma unroll
  for (int off = 1; off <= 32; off <<= 1) {
    int v = __shfl_down(s, off, 64);
    if (lane + off < 64) s += v;
  }
  if (lane == 0) wtot[wid] = s;
  __syncthreads();
  int above_w = 0;
  for (int w2 = wid + 1; w2 < 16; ++w2) above_w += wtot[w2];
  int incl = above_w + s;
  int above = incl - local;
  if (above < 128 && incl >= 128) {
    int cnt = above;
#pragma unroll
    for (int q = 7; q >= 0; --q) {
      int c = lc[q];
      if (cnt + c >= 128) { sT = base + q; break; }
      cnt += c;
    }
  }
  __syncthreads();
  int T = sT;
  for (int i = tid; i < N; i += 1024) {
    unsigned long long kk = keys[(size_t)tb * N + i];
    if ((int)(kk >> 51) >= T) {
      int pos = atomicAdd(&ncnt, 1);
      if (pos < CAP) cand[pos] = kk;
    }
  }
  __syncthreads();
  if (tid < 64) {
    int nc = ncnt < CAP ? ncnt : CAP;
    unsigned long long v[8];
#pragma unroll
    for (int r = 0; r < 8; ++r) {
      int e = r * 64 + lane;
      v[r] = (e < nc) ? cand[e] : 0ULL;
    }
    for (int k = 2; k <= 512; k <<= 1)
      for (int j = k >> 1; j > 0; j >>= 1) {
        if (j >= 64) {
          int rj = j >> 6;
#pragma unroll
          for (int r = 0; r < 8; ++r)
            if (!(r & rj)) {
              int r2 = r | rj;
              bool up = (((r * 64) & k) != 0);
              unsigned long long a = v[r], c = v[r2];
              bool sw = up ? (a > c) : (a < c);
              if (sw) { v[r] = c; v[r2] = a; }
            }
        } else {
#pragma unroll
          for (int r = 0; r < 8; ++r) {
            unsigned long long o = shfl_xor_u64(v[r], j);
            int e = r * 64 + lane;
            bool up = (e & k) != 0;
            bool lower = (lane & j) == 0;
            unsigned long long mn = v[r] < o ? v[r] : o;
            unsigned long long mx = v[r] < o ? o : v[r];
            v[r] = (lower == up) ? mn : mx;
          }
        }
      }
#pragma unroll
    for (int r = 0; r < 2; ++r) {
      int e = r * 64 + lane;
      unsigned long long kk = v[r];
      unsigned n = ~((unsigned)kk);
      unsigned u = (unsigned)(kk >> 32);
      float sc = (u & 0x80000000u) ? __uint_as_float(u & 0x7FFFFFFFu)
                                   : __uint_as_float(~u);
      idx_sel[tb * 128 + e] = (int)n;
      gate_sel[tb * 128 + e] = tanhf(sc);
    }
  }
}

// ------- whole W GRU chain (8 steps) in one kernel; grid (2b, 64 jtiles) ----
// j-tile = 2: per-j math identical, 2x block parallelism vs R9.
template <int SRC_BF16>
__global__ __launch_bounds__(256) void wchain_kernel(
    const void* __restrict__ srcv, size_t src_tstride, size_t src_bstride,
    const int* __restrict__ idx_sel, const float* __restrict__ gate_sel,
    const float* __restrict__ Winit,   // [FF m][FF j]; h[j][m] = Winit[m][j]
    const float* __restrict__ wih, const float* __restrict__ whh,
    const float* __restrict__ bih, const float* __restrict__ bhh,
    float* __restrict__ snap) {        // [t*2+b][k][j]
  int b = blockIdx.x, j0 = blockIdx.y * 2;
  int tid = threadIdx.x, side = tid >> 7, kl = tid & 127;
  __shared__ float pooled[2][FF];
  __shared__ float hbuf[2][FF];
  __shared__ float ghbuf[3][2][FF];
  for (int e = tid; e < 2 * FF; e += 256) {
    int j = e >> 7, m = e & 127;
    hbuf[j][m] = Winit[m * FF + j0 + j];
  }
  float b0 = side ? bhh[kl] : bih[kl];
  float b1 = side ? bhh[FF + kl] : bih[FF + kl];
  float b2 = side ? bhh[2 * FF + kl] : bih[2 * FF + kl];
  const float* wmat = side ? whh : wih;
  const float4* w0p = (const float4*)(wmat + (size_t)(0 * FF + kl) * FF);
  const float4* w1p = (const float4*)(wmat + (size_t)(1 * FF + kl) * FF);
  const float4* w2p = (const float4*)(wmat + (size_t)(2 * FF + kl) * FF);
  for (int t = 0; t < TT; ++t) {
    int tb = t * 2 + b;
    __syncthreads();   // protects pooled overwrite + hbuf update visibility
    for (int e = tid; e < 2 * FF; e += 256) {
      int j = e >> 7, m = e & 127;
      int n = idx_sel[tb * 128 + j0 + j];
      float g = gate_sel[tb * 128 + j0 + j];
      size_t off = (size_t)t * src_tstride + (size_t)b * src_bstride +
                   (size_t)n * FF + m;
      float xv;
      if constexpr (SRC_BF16) xv = bf2f(((const unsigned short*)srcv)[off]);
      else                    xv = ((const float*)srcv)[off];
      pooled[j][m] = xv * g;
    }
    __syncthreads();
    const float4* vsrc = (const float4*)(side ? &hbuf[0][0] : &pooled[0][0]);
    float acc0[2] = {}, acc1[2] = {}, acc2[2] = {};
    for (int mq = 0; mq < 32; ++mq) {
      float4 w0 = w0p[mq], w1 = w1p[mq], w2 = w2p[mq];
#pragma unroll
      for (int j = 0; j < 2; ++j) {
        float4 v = vsrc[j * 32 + mq];
        acc0[j] += v.x * w0.x + v.y * w0.y + v.z * w0.z + v.w * w0.w;
        acc1[j] += v.x * w1.x + v.y * w1.y + v.z * w1.z + v.w * w1.w;
        acc2[j] += v.x * w2.x + v.y * w2.y + v.z * w2.z + v.w * w2.w;
      }
    }
    if (side) {
#pragma unroll
      for (int j = 0; j < 2; ++j) {
        ghbuf[0][j][kl] = acc0[j] + b0;
        ghbuf[1][j][kl] = acc1[j] + b1;
        ghbuf[2][j][kl] = acc2[j] + b2;
      }
    }
    __syncthreads();
    if (!side) {
#pragma unroll
      for (int j = 0; j < 2; ++j) {
        float rr = 1.0f / (1.0f + expf(-(acc0[j] + b0 + ghbuf[0][j][kl])));
        float zz = 1.0f / (1.0f + expf(-(acc1[j] + b1 + ghbuf[1][j][kl])));
        float nn = tanhf(acc2[j] + b2 + rr * ghbuf[2][j][kl]);
        float h = hbuf[j][kl];
        float hn = (1.0f - zz) * nn + zz * h;
        hbuf[j][kl] = hn;
        snap[((size_t)tb * FF + kl) * FF + j0 + j] = hn;
      }
    }
  }
}

// ------- batched GEMM + bias + relu (+ optional fused next-layer scores) ----
// out[tb][n][:] = relu(A[tb][n][:] @ Wsnap[tb] + bias); grid (ceil(N/128), 2b, Tz)
// Output: fp32 (outf) or bf16 (outb) — exactly one non-null.
__global__ __launch_bounds__(256) void gemm_kernel(
    const float* __restrict__ A, size_t a_tstride, size_t a_bstride,
    const float* __restrict__ Wsnap, const float* __restrict__ bias,
    float* __restrict__ outf, unsigned short* __restrict__ outb,
    size_t o_tstride, size_t o_bstride,
    const float* __restrict__ p1, const float* __restrict__ pinv1,
    unsigned long long* __restrict__ keys, int* __restrict__ hist, int N) {
  int nb = blockIdx.x, b = blockIdx.y, t = blockIdx.z;
  int tb = t * 2 + b;
  __shared__ float As[128][33];    // row-major, +1 pad: conflict-free staging
  __shared__ float Bs[32][128];
  __shared__ float spart[128][17];
  __shared__ float p1s[128];
  int tid = threadIdx.x;
  int tc = tid & 15, tr = tid >> 4;
  if (p1 && tid < 128) p1s[tid] = p1[tid];
  float acc[8][8] = {};
  const float* Ab = A + (size_t)t * a_tstride + (size_t)b * a_bstride;
  const float* Wb = Wsnap + (size_t)tb * FF * FF;
  for (int kc = 0; kc < 4; ++kc) {
    int k0 = kc * 32;
    __syncthreads();
    for (int e = tid; e < 128 * 32; e += 256) {
      int r = e >> 5, kk = e & 31;
      int n = nb * 128 + r;
      As[r][kk] = (n < N) ? Ab[(size_t)n * FF + k0 + kk] : 0.f;
    }
    for (int e = tid; e < 32 * 128; e += 256) {
      int r = e >> 7, dd = e & 127;
      Bs[r][dd] = Wb[(k0 + r) * FF + dd];
    }
    __syncthreads();
#pragma unroll 4
    for (int kk = 0; kk < 32; ++kk) {
      float av[8];
#pragma unroll
      for (int i = 0; i < 8; ++i) av[i] = As[tr * 8 + i][kk];
      const float4* brow = (const float4*)Bs[kk];
      float4 b0 = brow[tc * 2], b1 = brow[tc * 2 + 1];
      float bv[8] = {b0.x, b0.y, b0.z, b0.w, b1.x, b1.y, b1.z, b1.w};
#pragma unroll
      for (int i = 0; i < 8; ++i)
#pragma unroll
        for (int j = 0; j < 8; ++j) acc[i][j] += av[i] * bv[j];
    }
  }
  float bb[8];
#pragma unroll
  for (int j = 0; j < 8; ++j) bb[j] = bias[tc * 8 + j];
  size_t obase = (size_t)t * o_tstride + (size_t)b * o_bstride;
#pragma unroll
  for (int i = 0; i < 8; ++i) {
    int n = nb * 128 + tr * 8 + i;
    float v[8]; float part = 0.f;
#pragma unroll
    for (int j = 0; j < 8; ++j) {
      v[j] = fmaxf(acc[i][j] + bb[j], 0.f);
      if (p1) part += v[j] * p1s[tc * 8 + j];
    }
    if (n < N) {
      if (outb) {
        unsigned short* dst = outb + obase + (size_t)n * FF + tc * 8;
        uint4 pk;
        pk.x = (unsigned)f2bf(v[0]) | ((unsigned)f2bf(v[1]) << 16);
        pk.y = (unsigned)f2bf(v[2]) | ((unsigned)f2bf(v[3]) << 16);
        pk.z = (unsigned)f2bf(v[4]) | ((unsigned)f2bf(v[5]) << 16);
        pk.w = (unsigned)f2bf(v[6]) | ((unsigned)f2bf(v[7]) << 16);
        *(uint4*)dst = pk;
      } else {
        float4* dst = (float4*)(outf + obase + (size_t)n * FF + tc * 8);
        dst[0] = make_float4(v[0], v[1], v[2], v[3]);
        dst[1] = make_float4(v[4], v[5], v[6], v[7]);
      }
    }
    if (p1) spart[tr * 8 + i][tc] = part;
  }
  if (p1) {
    __syncthreads();
    if (tid < 128) {
      int n = nb * 128 + tid;
      if (n < N) {
        float s = 0.f;
#pragma unroll
        for (int q = 0; q < 16; ++q) s += spart[tid][q];
        s *= *pinv1;
        unsigned u = __float_as_uint(s);
        u = (u & 0x80000000u) ? ~u : (u | 0x80000000u);
        keys[(size_t)tb * N + n] = ((unsigned long long)u << 32) | (unsigned)(~n);
        atomicAdd(&hist[tb * BINS + (u >> 19)], 1);
      }
    }
  }
}

// ---------------- host ----------------
extern "C" void kernel_launch(void* const* d_in, const int* in_sizes, int n_in,
                              void* d_out, int out_size, void* d_ws, size_t ws_size,
                              hipStream_t stream) {
  const float* x   = (const float*)d_in[0];
  const void*  ei  = d_in[1];
  const float* ew  = (const float*)d_in[2];
  const float* W0  = (const float*)d_in[3];
  const float* p   = (const float*)d_in[4];
  const float* wih = (const float*)d_in[5];
  const float* whh = (const float*)d_in[6];
  const float* bih = (const float*)d_in[7];
  const float* bhh = (const float*)d_in[8];
  const float* bias= (const float*)d_in[9];

  const int E  = in_sizes[2];
  const int N  = in_sizes[0] / (BB * TT * FF);
  const int EN = E + N;
  const size_t NF = (size_t)N * FF;
  const int NG = (N + 3) / 4;

  char* w = (char*)d_ws;
  auto alloc = [&](size_t bytes) -> char* {
    char* r = w; w += (bytes + 255) & ~(size_t)255; return r;
  };
  // ---- zero region (single memset) ----
  char* zbeg = w;
  float* deg      = (float*)alloc((size_t)N * 4);
  int*   counts   = (int*)  alloc((size_t)N * 4);
  int*   cursors  = (int*)  alloc((size_t)N * 4);
  int*   flag     = (int*)  alloc(4);
  int*   hist     = (int*)  alloc((size_t)2 * TT * BB * BINS * 4);
  char* zend = w;
  // ---- rest ----
  int*   offsets  = (int*)  alloc((size_t)(N + 1) * 4);
  float* dinv     = (float*)alloc((size_t)N * 4);
  float* pinv     = (float*)alloc(2 * 4);
  int2*  ep       = (int2*) alloc((size_t)EN * 8);
  unsigned long long* keys0 = (unsigned long long*)alloc((size_t)TT * BB * N * 8);
  unsigned long long* keys1 = (unsigned long long*)alloc((size_t)TT * BB * N * 8);
  int*   idx0     = (int*)  alloc((size_t)TT * BB * 128 * 4);
  float* gate0    = (float*)alloc((size_t)TT * BB * 128 * 4);
  int*   idx1     = (int*)  alloc((size_t)TT * BB * 128 * 4);
  float* gate1    = (float*)alloc((size_t)TT * BB * 128 * 4);
  float* W0snap   = (float*)alloc((size_t)TT * BB * FF * FF * 4);
  float* W1snap   = (float*)alloc((size_t)TT * BB * FF * FF * 4);
  float* xp       = (float*)alloc((size_t)TT * BB * NF * 4);  // A·x[t], fp32
  unsigned short* act0 = (unsigned short*)alloc((size_t)TT * BB * NF * 2); // bf16
  float* xq       = (float*)alloc((size_t)BB * NF * 4);       // A·act0[7], fp32
  int* hist0 = hist;
  int* hist1 = hist + (size_t)TT * BB * BINS;

  hipMemsetAsync(zbeg, 0, (size_t)(zend - zbeg), stream);

  // graph preprocessing (CSR by destination + symmetric norm)
  prep_kernel<<<3, 256, 0, stream>>>((const int*)ei, E, flag, p, pinv);
  hist_kernel<<<(EN + 255) / 256, 256, 0, stream>>>(ei, flag, E, N, ew, deg, counts);
  scan_kernel<<<1, 1024, 0, stream>>>(counts, deg, offsets, dinv, N, EN);
  scatter_kernel<<<(EN + 255) / 256, 256, 0, stream>>>(ei, flag, E, N, ew, dinv,
                                                       offsets, cursors, ep);

  // xp[t][b] = A · x[b][t]: 4 fq passes x 8 t, t pinned to XCD (R9 layout)
  prop_kernel<0><<<NG * 4 * TT, 256, 0, stream>>>(
      x, NF, (size_t)TT * NF, xp, (size_t)BB * NF, NF,
      ep, offsets, p, pinv, keys0, hist0, N, NG, 1);

  selectsort_kernel<<<dim3(BB, TT), 1024, 0, stream>>>(
      keys0, hist0, N, idx0, gate0);

  // whole layer-0 W chain (8 GRU steps), j-tile 2
  wchain_kernel<0><<<dim3(BB, 64), 256, 0, stream>>>(
      x, NF, (size_t)TT * NF, idx0, gate0, W0,
      wih, whh, bih, bhh, W0snap);

  // act0[t][b] = relu(xp @ W0_t + bias0) -> bf16, fused layer-1 scores (fp32)
  gemm_kernel<<<dim3((N + 127) / 128, BB, TT), 256, 0, stream>>>(
      xp, (size_t)BB * NF, NF, W0snap, bias,
      nullptr, act0, (size_t)BB * NF, NF,
      p + FF, pinv + 1, keys1, hist1, N);

  selectsort_kernel<<<dim3(BB, TT), 1024, 0, stream>>>(
      keys1, hist1, N, idx1, gate1);

  // layer-1 W chain (bf16 pooled gathers), j-tile 2
  wchain_kernel<1><<<dim3(BB, 64), 256, 0, stream>>>(
      act0, (size_t)BB * NF, NF, idx1, gate1, W0 + FF * FF,
      wih + (size_t)GG * FF, whh + (size_t)GG * FF,
      bih + GG, bhh + GG, W1snap);

  // xq[b] = A · act0[7][b]  (bf16 gather, fp32 accumulate; 2 fq passes)
  prop_kernel<1><<<NG * 2, 256, 0, stream>>>(
      act0 + (size_t)(TT - 1) * BB * NF, 0, NF, xq, 0, NF,
      ep, offsets, nullptr, nullptr, nullptr, nullptr, N, NG, 0);

  // d_out = relu(xq @ W1_7 + bias1), fp32
  gemm_kernel<<<dim3((N + 127) / 128, BB, 1), 256, 0, stream>>>(
      xq, 0, NF, W1snap + (size_t)(TT - 1) * BB * FF * FF, bias + FF,
      (float*)d_out, nullptr, 0, NF,
      nullptr, nullptr, nullptr, nullptr, N);
}

// Round 12
// 806.583 us; speedup vs baseline: 1.1760x; 1.0207x over previous
//
#include <hip/hip_runtime.h>
#include <hip/hip_bf16.h>
#include <math.h>

// EvolveGCN-H on MI355X. B=2, T=8, N=10000, F=128, E=320000, 2 layers.
// R12: GRU split — gi (t-parallel) precomputed for all 16 (t,b) in one
// coalesced gathered-GEMM (gipre); serial chain reduced to gh-only wlite
// (256 blocks, whh L1-resident row streams, 2 barriers/t). Replaces wchain's
// pathological 64-line/instr weight reads at half-idle occupancy.

#define BB 2
#define TT 8
#define FF 128
#define GG 384   // 3*FF
#define BINS 8192
#define CAP 512

typedef float v4f __attribute__((ext_vector_type(4)));

__device__ __forceinline__ float bf2f(unsigned short u) {
  return __uint_as_float((unsigned)u << 16);
}
__device__ __forceinline__ unsigned short f2bf(float f) {  // RNE
  unsigned x = __float_as_uint(f);
  unsigned r = ((x >> 16) & 1u) + 0x7fffu;
  return (unsigned short)((x + r) >> 16);
}

// ---------------- detect (int64 vs int32) + pnorm, one dispatch -------------
__global__ void prep_kernel(const int* __restrict__ ei32, int E, int* __restrict__ flag,
                            const float* __restrict__ p, float* __restrict__ pinv) {
  if (blockIdx.x == 0) {
    int step = E / 256;
    int e = threadIdx.x * step;
    if (ei32[2 * e + 1] != 0) *flag = 1;   // benign race, same value
  } else {
    int c = blockIdx.x - 1, tid = threadIdx.x;
    float s = 0.f;
    if (tid < 128) { float v = p[c * FF + tid]; s = v * v; }
    for (int o = 32; o; o >>= 1) s += __shfl_xor(s, o, 64);
    __shared__ float red[4];
    if ((tid & 63) == 0) red[tid >> 6] = s;
    __syncthreads();
    if (tid == 0) pinv[c] = 1.0f / sqrtf(red[0] + red[1] + red[2] + red[3]);
  }
}

__device__ __forceinline__ void edge_fetch(const void* ei, int is32, int E,
                                           int e, const float* ew,
                                           int& row, int& col, float& w) {
  if (e < E) {
    if (is32) {
      const int* p = (const int*)ei;
      row = p[e]; col = p[E + e];
    } else {
      const long long* p = (const long long*)ei;
      row = (int)p[e]; col = (int)p[(long long)E + e];
    }
    w = ew[e];
  } else {           // self loop
    row = col = e - E; w = 1.0f;
  }
}

__global__ void hist_kernel(const void* ei, const int* flag, int E, int N,
                            const float* __restrict__ ew,
                            float* __restrict__ deg, int* __restrict__ counts) {
  int e = blockIdx.x * 256 + threadIdx.x;
  if (e >= E + N) return;
  int row, col; float w;
  edge_fetch(ei, *flag, E, e, ew, row, col, w);
  atomicAdd(&deg[col], w);
  atomicAdd(&counts[col], 1);
}

// ---- offsets scan (shuffle-based, 1 barrier) + dinv, one dispatch ----------
__global__ __launch_bounds__(1024) void scan_kernel(
    const int* __restrict__ counts, const float* __restrict__ deg,
    int* __restrict__ offsets, float* __restrict__ dinv, int N, int EN) {
  __shared__ int wtot[16];
  int tid = threadIdx.x, lane = tid & 63, wid = tid >> 6;
  int base = tid * 10;
  int lc[10]; int s10 = 0;
#pragma unroll
  for (int q = 0; q < 10; ++q) {
    int idx = base + q;
    int cv = (idx < N) ? counts[idx] : 0;
    lc[q] = cv; s10 += cv;
    if (idx < N) {
      float d = deg[idx];
      dinv[idx] = (d > 0.f) ? 1.0f / sqrtf(d) : 0.f;
    }
  }
  int s = s10;
#pragma unroll
  for (int off = 1; off <= 32; off <<= 1) {
    int v = __shfl_up(s, off, 64);
    if (lane >= off) s += v;
  }
  if (lane == 63) wtot[wid] = s;
  __syncthreads();
  int pre = 0;
  for (int w2 = 0; w2 < wid; ++w2) pre += wtot[w2];
  int run = pre + s - s10;   // exclusive prefix
#pragma unroll
  for (int q = 0; q < 10; ++q) {
    int idx = base + q;
    if (idx < N) { offsets[idx] = run; run += lc[q]; }
  }
  if (tid == 0) offsets[N] = EN;
}

__global__ void scatter_kernel(const void* ei, const int* flag, int E, int N,
                               const float* __restrict__ ew,
                               const float* __restrict__ dinv,
                               const int* __restrict__ offs,
                               int* __restrict__ cursors,
                               int2* __restrict__ ep) {
  int e = blockIdx.x * 256 + threadIdx.x;
  if (e >= E + N) return;
  int row, col; float w;
  edge_fetch(ei, *flag, E, e, ew, row, col, w);
  int pos = atomicAdd(&cursors[col], 1);
  ep[offs[col] + pos] = make_int2(row, __float_as_int(dinv[row] * w * dinv[col]));
}

// ------- CSR prop, locality-engineered (R9 structure) -----------------------
template <int SRC_BF16>
__global__ __launch_bounds__(256) void prop_kernel(
    const void* __restrict__ srcv, size_t s_tstride, size_t s_bstride,
    float* __restrict__ dst, size_t d_tstride, size_t d_bstride,
    const int2* __restrict__ ep, const int* __restrict__ offs,
    const float* __restrict__ p, const float* __restrict__ pinv,
    unsigned long long* __restrict__ keys, int* __restrict__ hist,
    int N, int NG, int t8) {
  constexpr int PER = SRC_BF16 ? 8 : 4;      // feats per lane per pass
  constexpr int RSU = SRC_BF16 ? 16 : 32;    // row stride in 16B units
  int lid = blockIdx.x;
  int t, s;
  if (t8) { t = lid & 7; s = lid >> 3; } else { t = 0; s = lid; }
  int fq = s / NG, vg = s - fq * NG;
  int lane = threadIdx.x & 63;
  int e = lane >> 3, sub = lane & 7;
  int v = vg * 4 + (threadIdx.x >> 6);
  if (v >= N) return;
  int e0 = offs[v], e1 = offs[v + 1];
  size_t o0 = (size_t)t * s_tstride, o1 = o0 + s_bstride;
  const uint4* g0;
  const uint4* g1;
  if constexpr (SRC_BF16) {
    g0 = (const uint4*)((const unsigned short*)srcv + o0);
    g1 = (const uint4*)((const unsigned short*)srcv + o1);
  } else {
    g0 = (const uint4*)((const float*)srcv + o0);
    g1 = (const uint4*)((const float*)srcv + o1);
  }
  int fqs = fq * 8;   // subword offset of this pass
  float acc0[PER], acc1[PER];
#pragma unroll
  for (int q = 0; q < PER; ++q) { acc0[q] = 0.f; acc1[q] = 0.f; }
  for (int base = e0; base < e1; base += 64) {
    int cnt = e1 - base; if (cnt > 64) cnt = 64;
    int2 m = make_int2(0, 0);
    if (lane < cnt) m = ep[base + lane];
    for (int i = 0; i < cnt; i += 8) {
      int srcl = i + e;
      int row = __shfl(m.x, srcl, 64);
      float wv = __int_as_float(__shfl(m.y, srcl, 64));
      if (srcl >= cnt) wv = 0.f;
      size_t r = (size_t)row * RSU + fqs + sub;
      uint4 ra = g0[r], rb = g1[r];
      if constexpr (SRC_BF16) {
        acc0[0] += wv * bf2f(ra.x & 0xffff); acc0[1] += wv * bf2f(ra.x >> 16);
        acc0[2] += wv * bf2f(ra.y & 0xffff); acc0[3] += wv * bf2f(ra.y >> 16);
        acc0[4] += wv * bf2f(ra.z & 0xffff); acc0[5] += wv * bf2f(ra.z >> 16);
        acc0[6] += wv * bf2f(ra.w & 0xffff); acc0[7] += wv * bf2f(ra.w >> 16);
        acc1[0] += wv * bf2f(rb.x & 0xffff); acc1[1] += wv * bf2f(rb.x >> 16);
        acc1[2] += wv * bf2f(rb.y & 0xffff); acc1[3] += wv * bf2f(rb.y >> 16);
        acc1[4] += wv * bf2f(rb.z & 0xffff); acc1[5] += wv * bf2f(rb.z >> 16);
        acc1[6] += wv * bf2f(rb.w & 0xffff); acc1[7] += wv * bf2f(rb.w >> 16);
      } else {
        acc0[0] += wv * __uint_as_float(ra.x);
        acc0[1] += wv * __uint_as_float(ra.y);
        acc0[2] += wv * __uint_as_float(ra.z);
        acc0[3] += wv * __uint_as_float(ra.w);
        acc1[0] += wv * __uint_as_float(rb.x);
        acc1[1] += wv * __uint_as_float(rb.y);
        acc1[2] += wv * __uint_as_float(rb.z);
        acc1[3] += wv * __uint_as_float(rb.w);
      }
    }
  }
#pragma unroll
  for (int mk = 8; mk <= 32; mk <<= 1) {
#pragma unroll
    for (int q = 0; q < PER; ++q) {
      acc0[q] += __shfl_xor(acc0[q], mk, 64);
      acc1[q] += __shfl_xor(acc1[q], mk, 64);
    }
  }
  if (e < 2) {
    float* ob = dst + (size_t)t * d_tstride + (e ? d_bstride : 0);
    float* av = e ? acc1 : acc0;
    size_t fo = (size_t)v * FF + fq * (PER * 8) + sub * PER;
    v4f st0 = {av[0], av[1], av[2], av[3]};
    __builtin_nontemporal_store(st0, (v4f*)(ob + fo));
    if constexpr (SRC_BF16) {
      v4f st1 = {av[4], av[5], av[6], av[7]};
      __builtin_nontemporal_store(st1, (v4f*)(ob + fo + 4));
    }
  }
  if constexpr (!SRC_BF16) {
    if (p && fq == 0) {
      int half = lane >> 5, i32 = lane & 31;
      const v4f* xrow = (const v4f*)(half ? g1 : g0);
      v4f xv = __builtin_nontemporal_load(xrow + (size_t)v * 32 + i32);
      float4 pp = ((const float4*)p)[i32];
      float sc = xv.x * pp.x + xv.y * pp.y + xv.z * pp.z + xv.w * pp.w;
#pragma unroll
      for (int o = 1; o <= 16; o <<= 1) sc += __shfl_xor(sc, o, 64);
      if (i32 == 0) {
        float ss = sc * (*pinv);
        unsigned u = __float_as_uint(ss);
        u = (u & 0x80000000u) ? ~u : (u | 0x80000000u);
        int tb = t * 2 + half;
        keys[(size_t)tb * N + v] = ((unsigned long long)u << 32) | (unsigned)(~v);
        atomicAdd(&hist[tb * BINS + (u >> 19)], 1);
      }
    }
  }
}

// ------- select threshold + filter + wave-register sort; grid (2b, 8t) -----
__device__ __forceinline__ unsigned long long shfl_xor_u64(unsigned long long x,
                                                           int m) {
  unsigned lo = (unsigned)x, hi = (unsigned)(x >> 32);
  lo = __shfl_xor(lo, m, 64);
  hi = __shfl_xor(hi, m, 64);
  return ((unsigned long long)hi << 32) | lo;
}

__global__ __launch_bounds__(1024) void selectsort_kernel(
    const unsigned long long* __restrict__ keys, const int* __restrict__ hist,
    int N, int* __restrict__ idx_sel, float* __restrict__ gate_sel) {
  int tb = blockIdx.y * 2 + blockIdx.x, tid = threadIdx.x;
  int lane = tid & 63, wid = tid >> 6;   // 16 waves
  const int* h = hist + tb * BINS;
  __shared__ int wtot[16];
  __shared__ unsigned long long cand[CAP];
  __shared__ int sT, ncnt;
  int base = tid * 8;
  int lc[8]; int local = 0;
#pragma unroll
  for (int q = 0; q < 8; ++q) { lc[q] = h[base + q]; local += lc[q]; }
  if (tid == 0) ncnt = 0;
  int s = local;
#pragma unroll
  for (int off = 1; off <= 32; off <<= 1) {
    int v = __shfl_down(s, off, 64);
    if (lane + off < 64) s += v;
  }
  if (lane == 0) wtot[wid] = s;
  __syncthreads();
  int above_w = 0;
  for (int w2 = wid + 1; w2 < 16; ++w2) above_w += wtot[w2];
  int incl = above_w + s;
  int above = incl - local;
  if (above < 128 && incl >= 128) {
    int cnt = above;
#pragma unroll
    for (int q = 7; q >= 0; --q) {
      int c = lc[q];
      if (cnt + c >= 128) { sT = base + q; break; }
      cnt += c;
    }
  }
  __syncthreads();
  int T = sT;
  for (int i = tid; i < N; i += 1024) {
    unsigned long long kk = keys[(size_t)tb * N + i];
    if ((int)(kk >> 51) >= T) {
      int pos = atomicAdd(&ncnt, 1);
      if (pos < CAP) cand[pos] = kk;
    }
  }
  __syncthreads();
  if (tid < 64) {
    int nc = ncnt < CAP ? ncnt : CAP;
    unsigned long long v[8];
#pragma unroll
    for (int r = 0; r < 8; ++r) {
      int e = r * 64 + lane;
      v[r] = (e < nc) ? cand[e] : 0ULL;
    }
    for (int k = 2; k <= 512; k <<= 1)
      for (int j = k >> 1; j > 0; j >>= 1) {
        if (j >= 64) {
          int rj = j >> 6;
#pragma unroll
          for (int r = 0; r < 8; ++r)
            if (!(r & rj)) {
              int r2 = r | rj;
              bool up = (((r * 64) & k) != 0);
              unsigned long long a = v[r], c = v[r2];
              bool sw = up ? (a > c) : (a < c);
              if (sw) { v[r] = c; v[r2] = a; }
            }
        } else {
#pragma unroll
          for (int r = 0; r < 8; ++r) {
            unsigned long long o = shfl_xor_u64(v[r], j);
            int e = r * 64 + lane;
            bool up = (e & k) != 0;
            bool lower = (lane & j) == 0;
            unsigned long long mn = v[r] < o ? v[r] : o;
            unsigned long long mx = v[r] < o ? o : v[r];
            v[r] = (lower == up) ? mn : mx;
          }
        }
      }
#pragma unroll
    for (int r = 0; r < 2; ++r) {
      int e = r * 64 + lane;
      unsigned long long kk = v[r];
      unsigned n = ~((unsigned)kk);
      unsigned u = (unsigned)(kk >> 32);
      float sc = (u & 0x80000000u) ? __uint_as_float(u & 0x7FFFFFFFu)
                                   : __uint_as_float(~u);
      idx_sel[tb * 128 + e] = (int)n;
      gate_sel[tb * 128 + e] = tanhf(sc);
    }
  }
}

// ------- gi precompute: gi[tb][j][gk] = pooled_tb[j,:]·wih[gk,:] + bih -------
// grid (3 gates, 2 b, 8 t); 256 thr; gathered-A 128x128 GEMM per block.
template <int SRC_BF16>
__global__ __launch_bounds__(256) void gipre_kernel(
    const void* __restrict__ srcv, size_t src_tstride, size_t src_bstride,
    const int* __restrict__ idx_sel, const float* __restrict__ gate_sel,
    const float* __restrict__ wih, const float* __restrict__ bih,
    float* __restrict__ gi) {
  int g = blockIdx.x, b = blockIdx.y, t = blockIdx.z;
  int tb = t * 2 + b, gbase = g * 128;
  __shared__ float As[128][33];
  __shared__ float Bs[128][33];
  __shared__ int s_idx[128];
  __shared__ float s_gate[128];
  int tid = threadIdx.x;
  int tc = tid & 15, tr = tid >> 4;
  if (tid < 128) {
    s_idx[tid] = idx_sel[tb * 128 + tid];
    s_gate[tid] = gate_sel[tb * 128 + tid];
  }
  float acc[8][8] = {};
  const char* srcb = (const char*)srcv;
  size_t sbase = (size_t)t * src_tstride + (size_t)b * src_bstride;
  for (int kc = 0; kc < 4; ++kc) {
    int k0 = kc * 32;
    __syncthreads();
    for (int e = tid; e < 128 * 32; e += 256) {
      int j = e >> 5, kk = e & 31;
      size_t off = sbase + (size_t)s_idx[j] * FF + k0 + kk;
      float xv;
      if constexpr (SRC_BF16) xv = bf2f(((const unsigned short*)srcb)[off]);
      else                    xv = ((const float*)srcb)[off];
      As[j][kk] = xv * s_gate[j];
    }
    for (int e = tid; e < 128 * 32; e += 256) {
      int r = e >> 5, kk = e & 31;
      Bs[r][kk] = wih[(size_t)(gbase + r) * FF + k0 + kk];
    }
    __syncthreads();
#pragma unroll 4
    for (int kk = 0; kk < 32; ++kk) {
      float av[8], bv[8];
#pragma unroll
      for (int i = 0; i < 8; ++i) av[i] = As[tr * 8 + i][kk];
#pragma unroll
      for (int j = 0; j < 8; ++j) bv[j] = Bs[tc * 8 + j][kk];
#pragma unroll
      for (int i = 0; i < 8; ++i)
#pragma unroll
        for (int j = 0; j < 8; ++j) acc[i][j] += av[i] * bv[j];
    }
  }
  float bb[8];
#pragma unroll
  for (int j = 0; j < 8; ++j) bb[j] = bih[gbase + tc * 8 + j];
#pragma unroll
  for (int i = 0; i < 8; ++i) {
    float* dst = gi + (size_t)(tb * 128 + tr * 8 + i) * GG + gbase + tc * 8;
    float4* d4 = (float4*)dst;
    d4[0] = make_float4(acc[i][0] + bb[0], acc[i][1] + bb[1],
                        acc[i][2] + bb[2], acc[i][3] + bb[3]);
    d4[1] = make_float4(acc[i][4] + bb[4], acc[i][5] + bb[5],
                        acc[i][6] + bb[6], acc[i][7] + bb[7]);
  }
}

// ------- serial gh chain only; grid (2 b, 128 j), 384 thr = 3 gates x 128 k -
__global__ __launch_bounds__(384) void wlite_kernel(
    const float* __restrict__ gi,
    const float* __restrict__ Winit,   // [FF m][FF j]; h[m] = Winit[m][j]
    const float* __restrict__ whh, const float* __restrict__ bhh,
    float* __restrict__ snap) {        // [t*2+b][k][j]
  int b = blockIdx.x, j = blockIdx.y;
  int tid = threadIdx.x, g = tid >> 7, k = tid & 127;
  __shared__ float hbuf[FF];
  __shared__ float gh3[3][FF];
  if (tid < 128) hbuf[tid] = Winit[tid * FF + j];
  float bh = bhh[g * 128 + k];
  const float4* wrow = (const float4*)(whh + (size_t)(g * 128 + k) * FF);
  __syncthreads();
  for (int t = 0; t < TT; ++t) {
    int tb = t * 2 + b;
    // gh_g[k] = dot(h, whh[g*128+k]) — h broadcast from LDS, w per-lane row
    const float4* h4 = (const float4*)hbuf;
    float acc = 0.f;
#pragma unroll 8
    for (int mq = 0; mq < 32; ++mq) {
      float4 hv = h4[mq], wv = wrow[mq];
      acc += hv.x * wv.x + hv.y * wv.y + hv.z * wv.z + hv.w * wv.w;
    }
    gh3[g][k] = acc + bh;
    __syncthreads();
    if (g == 0) {
      size_t row = (size_t)(tb * 128 + j) * GG;
      float gir = gi[row + k], giz = gi[row + 128 + k], gin = gi[row + 256 + k];
      float rr = 1.0f / (1.0f + expf(-(gir + gh3[0][k])));
      float zz = 1.0f / (1.0f + expf(-(giz + gh3[1][k])));
      float nn = tanhf(gin + rr * gh3[2][k]);
      float h = hbuf[k];
      float hn = (1.0f - zz) * nn + zz * h;
      hbuf[k] = hn;
      snap[((size_t)tb * FF + k) * FF + j] = hn;
    }
    __syncthreads();
  }
}

// ------- batched GEMM + bias + relu (+ optional fused next-layer scores) ----
__global__ __launch_bounds__(256) void gemm_kernel(
    const float* __restrict__ A, size_t a_tstride, size_t a_bstride,
    const float* __restrict__ Wsnap, const float* __restrict__ bias,
    float* __restrict__ outf, unsigned short* __restrict__ outb,
    size_t o_tstride, size_t o_bstride,
    const float* __restrict__ p1, const float* __restrict__ pinv1,
    unsigned long long* __restrict__ keys, int* __restrict__ hist, int N) {
  int nb = blockIdx.x, b = blockIdx.y, t = blockIdx.z;
  int tb = t * 2 + b;
  __shared__ float As[128][33];    // row-major, +1 pad: conflict-free staging
  __shared__ float Bs[32][128];
  __shared__ float spart[128][17];
  __shared__ float p1s[128];
  int tid = threadIdx.x;
  int tc = tid & 15, tr = tid >> 4;
  if (p1 && tid < 128) p1s[tid] = p1[tid];
  float acc[8][8] = {};
  const float* Ab = A + (size_t)t * a_tstride + (size_t)b * a_bstride;
  const float* Wb = Wsnap + (size_t)tb * FF * FF;
  for (int kc = 0; kc < 4; ++kc) {
    int k0 = kc * 32;
    __syncthreads();
    for (int e = tid; e < 128 * 32; e += 256) {
      int r = e >> 5, kk = e & 31;
      int n = nb * 128 + r;
      As[r][kk] = (n < N) ? Ab[(size_t)n * FF + k0 + kk] : 0.f;
    }
    for (int e = tid; e < 32 * 128; e += 256) {
      int r = e >> 7, dd = e & 127;
      Bs[r][dd] = Wb[(k0 + r) * FF + dd];
    }
    __syncthreads();
#pragma unroll 4
    for (int kk = 0; kk < 32; ++kk) {
      float av[8];
#pragma unroll
      for (int i = 0; i < 8; ++i) av[i] = As[tr * 8 + i][kk];
      const float4* brow = (const float4*)Bs[kk];
      float4 b0 = brow[tc * 2], b1 = brow[tc * 2 + 1];
      float bv[8] = {b0.x, b0.y, b0.z, b0.w, b1.x, b1.y, b1.z, b1.w};
#pragma unroll
      for (int i = 0; i < 8; ++i)
#pragma unroll
        for (int j = 0; j < 8; ++j) acc[i][j] += av[i] * bv[j];
    }
  }
  float bb[8];
#pragma unroll
  for (int j = 0; j < 8; ++j) bb[j] = bias[tc * 8 + j];
  size_t obase = (size_t)t * o_tstride + (size_t)b * o_bstride;
#pragma unroll
  for (int i = 0; i < 8; ++i) {
    int n = nb * 128 + tr * 8 + i;
    float v[8]; float part = 0.f;
#pragma unroll
    for (int j = 0; j < 8; ++j) {
      v[j] = fmaxf(acc[i][j] + bb[j], 0.f);
      if (p1) part += v[j] * p1s[tc * 8 + j];
    }
    if (n < N) {
      if (outb) {
        unsigned short* dst = outb + obase + (size_t)n * FF + tc * 8;
        uint4 pk;
        pk.x = (unsigned)f2bf(v[0]) | ((unsigned)f2bf(v[1]) << 16);
        pk.y = (unsigned)f2bf(v[2]) | ((unsigned)f2bf(v[3]) << 16);
        pk.z = (unsigned)f2bf(v[4]) | ((unsigned)f2bf(v[5]) << 16);
        pk.w = (unsigned)f2bf(v[6]) | ((unsigned)f2bf(v[7]) << 16);
        *(uint4*)dst = pk;
      } else {
        float4* dst = (float4*)(outf + obase + (size_t)n * FF + tc * 8);
        dst[0] = make_float4(v[0], v[1], v[2], v[3]);
        dst[1] = make_float4(v[4], v[5], v[6], v[7]);
      }
    }
    if (p1) spart[tr * 8 + i][tc] = part;
  }
  if (p1) {
    __syncthreads();
    if (tid < 128) {
      int n = nb * 128 + tid;
      if (n < N) {
        float s = 0.f;
#pragma unroll
        for (int q = 0; q < 16; ++q) s += spart[tid][q];
        s *= *pinv1;
        unsigned u = __float_as_uint(s);
        u = (u & 0x80000000u) ? ~u : (u | 0x80000000u);
        keys[(size_t)tb * N + n] = ((unsigned long long)u << 32) | (unsigned)(~n);
        atomicAdd(&hist[tb * BINS + (u >> 19)], 1);
      }
    }
  }
}

// ---------------- host ----------------
extern "C" void kernel_launch(void* const* d_in, const int* in_sizes, int n_in,
                              void* d_out, int out_size, void* d_ws, size_t ws_size,
                              hipStream_t stream) {
  const float* x   = (const float*)d_in[0];
  const void*  ei  = d_in[1];
  const float* ew  = (const float*)d_in[2];
  const float* W0  = (const float*)d_in[3];
  const float* p   = (const float*)d_in[4];
  const float* wih = (const float*)d_in[5];
  const float* whh = (const float*)d_in[6];
  const float* bih = (const float*)d_in[7];
  const float* bhh = (const float*)d_in[8];
  const float* bias= (const float*)d_in[9];

  const int E  = in_sizes[2];
  const int N  = in_sizes[0] / (BB * TT * FF);
  const int EN = E + N;
  const size_t NF = (size_t)N * FF;
  const int NG = (N + 3) / 4;

  char* w = (char*)d_ws;
  auto alloc = [&](size_t bytes) -> char* {
    char* r = w; w += (bytes + 255) & ~(size_t)255; return r;
  };
  // ---- zero region (single memset) ----
  char* zbeg = w;
  float* deg      = (float*)alloc((size_t)N * 4);
  int*   counts   = (int*)  alloc((size_t)N * 4);
  int*   cursors  = (int*)  alloc((size_t)N * 4);
  int*   flag     = (int*)  alloc(4);
  int*   hist     = (int*)  alloc((size_t)2 * TT * BB * BINS * 4);
  char* zend = w;
  // ---- rest ----
  int*   offsets  = (int*)  alloc((size_t)(N + 1) * 4);
  float* dinv     = (float*)alloc((size_t)N * 4);
  float* pinv     = (float*)alloc(2 * 4);
  int2*  ep       = (int2*) alloc((size_t)EN * 8);
  unsigned long long* keys0 = (unsigned long long*)alloc((size_t)TT * BB * N * 8);
  unsigned long long* keys1 = (unsigned long long*)alloc((size_t)TT * BB * N * 8);
  int*   idx0     = (int*)  alloc((size_t)TT * BB * 128 * 4);
  float* gate0    = (float*)alloc((size_t)TT * BB * 128 * 4);
  int*   idx1     = (int*)  alloc((size_t)TT * BB * 128 * 4);
  float* gate1    = (float*)alloc((size_t)TT * BB * 128 * 4);
  float* W0snap   = (float*)alloc((size_t)TT * BB * FF * FF * 4);
  float* W1snap   = (float*)alloc((size_t)TT * BB * FF * FF * 4);
  float* gibuf    = (float*)alloc((size_t)TT * BB * 128 * GG * 4); // reused L0/L1
  float* xp       = (float*)alloc((size_t)TT * BB * NF * 4);  // A·x[t], fp32
  unsigned short* act0 = (unsigned short*)alloc((size_t)TT * BB * NF * 2); // bf16
  float* xq       = (float*)alloc((size_t)BB * NF * 4);       // A·act0[7], fp32
  int* hist0 = hist;
  int* hist1 = hist + (size_t)TT * BB * BINS;

  hipMemsetAsync(zbeg, 0, (size_t)(zend - zbeg), stream);

  // graph preprocessing (CSR by destination + symmetric norm)
  prep_kernel<<<3, 256, 0, stream>>>((const int*)ei, E, flag, p, pinv);
  hist_kernel<<<(EN + 255) / 256, 256, 0, stream>>>(ei, flag, E, N, ew, deg, counts);
  scan_kernel<<<1, 1024, 0, stream>>>(counts, deg, offsets, dinv, N, EN);
  scatter_kernel<<<(EN + 255) / 256, 256, 0, stream>>>(ei, flag, E, N, ew, dinv,
                                                       offsets, cursors, ep);

  // xp[t][b] = A · x[b][t]: 4 fq passes x 8 t, t pinned to XCD (R9 layout)
  prop_kernel<0><<<NG * 4 * TT, 256, 0, stream>>>(
      x, NF, (size_t)TT * NF, xp, (size_t)BB * NF, NF,
      ep, offsets, p, pinv, keys0, hist0, N, NG, 1);

  selectsort_kernel<<<dim3(BB, TT), 1024, 0, stream>>>(
      keys0, hist0, N, idx0, gate0);

  // layer-0 GRU: gi for all 16 (t,b) in parallel, then serial gh chain
  gipre_kernel<0><<<dim3(3, BB, TT), 256, 0, stream>>>(
      x, NF, (size_t)TT * NF, idx0, gate0, wih, bih, gibuf);
  wlite_kernel<<<dim3(BB, 128), 384, 0, stream>>>(
      gibuf, W0, whh, bhh, W0snap);

  // act0[t][b] = relu(xp @ W0_t + bias0) -> bf16, fused layer-1 scores (fp32)
  gemm_kernel<<<dim3((N + 127) / 128, BB, TT), 256, 0, stream>>>(
      xp, (size_t)BB * NF, NF, W0snap, bias,
      nullptr, act0, (size_t)BB * NF, NF,
      p + FF, pinv + 1, keys1, hist1, N);

  selectsort_kernel<<<dim3(BB, TT), 1024, 0, stream>>>(
      keys1, hist1, N, idx1, gate1);

  // layer-1 GRU (bf16 pooled gathers in gipre)
  gipre_kernel<1><<<dim3(3, BB, TT), 256, 0, stream>>>(
      act0, (size_t)BB * NF, NF, idx1, gate1,
      wih + (size_t)GG * FF, bih + GG, gibuf);
  wlite_kernel<<<dim3(BB, 128), 384, 0, stream>>>(
      gibuf, W0 + FF * FF, whh + (size_t)GG * FF, bhh + GG, W1snap);

  // xq[b] = A · act0[7][b]  (bf16 gather, fp32 accumulate; 2 fq passes)
  prop_kernel<1><<<NG * 2, 256, 0, stream>>>(
      act0 + (size_t)(TT - 1) * BB * NF, 0, NF, xq, 0, NF,
      ep, offsets, nullptr, nullptr, nullptr, nullptr, N, NG, 0);

  // d_out = relu(xq @ W1_7 + bias1), fp32
  gemm_kernel<<<dim3((N + 127) / 128, BB, 1), 256, 0, stream>>>(
      xq, 0, NF, W1snap + (size_t)(TT - 1) * BB * FF * FF, bias + FF,
      (float*)d_out, nullptr, 0, NF,
      nullptr, nullptr, nullptr, nullptr, N);
}